// Round 8
// baseline (221.558 us; speedup 1.0000x reference)
//
#include <hip/hip_runtime.h>
#include <math.h>
#include <stdint.h>

// ContentAttention fused, round 9 (resubmit — R7 bench died on infra, no
// verdict; R3 precedent: identical resubmission ran clean).
// R6 post-mortem: (a) VALUBusy double-counts MFMA (v_mfma_* are VALU) — the
// attn kernel is ~75% idle, pinned at the ~6.5-7 TB/s B-supply rate (512MB/
// 85us), not at any pipe; (b) total-attn = ~133us CONSTANT across all rounds
// == convert_k + 2nd launch — bigger than the attn kernel itself.
// v9 deletes convert_k: K fp32 read directly (same bytes/elem as hi+lo bf16,
// L3-resident), hi/lo split done in registers per body (split8 = exact same
// bf_split/pack_rn bit patterns -> numerics identical). Mask = K[:,0] direct.
// Engine otherwise v8: 1024 thr / 16 waves / BM=64 / acc[4][2], A hi/lo image
// in LDS staged per 512-k half, barrier-free halves, B raw-fp32 double-buffer
// in registers (float4[4], compile-time indexed).

#define NB 32
#define NQ 512
#define NK 512
#define ND 1024
#define BK 32
#define NT (ND / BK)            // 32 k-tiles
#define BM9 64                  // rows/block
#define ASTRIDE 520             // ushorts per A row (1040B; 2-way bank aliasing)

typedef __attribute__((ext_vector_type(8))) short short8;
typedef __attribute__((ext_vector_type(4))) float f32x4;
typedef __attribute__((ext_vector_type(4))) unsigned int uint32x4;

__device__ __forceinline__ void bf_split(float x, unsigned& hbits, float& lo) {
  unsigned u = __float_as_uint(x);
  unsigned r = u + 0x7fffu + ((u >> 16) & 1u);
  hbits = r & 0xffff0000u;
  lo = x - __uint_as_float(hbits);
}
__device__ __forceinline__ unsigned pack_rn(float x0, float x1) {
  unsigned u0 = __float_as_uint(x0), u1 = __float_as_uint(x1);
  unsigned r0 = u0 + 0x7fffu + ((u0 >> 16) & 1u);
  unsigned r1 = u1 + 0x7fffu + ((u1 >> 16) & 1u);
  return (r0 >> 16) | (r1 & 0xffff0000u);
}

// 8 consecutive fp32 (va,vb) -> bf16-hi frag + bf16-lo frag (MFMA operand
// order: elem i = k-index i; uint = [lo16: elem 2j, hi16: elem 2j+1]).
__device__ __forceinline__ void split8(const float4& va, const float4& vb,
                                       short8& hi, short8& lo) {
  unsigned h0, h1, h2, h3, h4, h5, h6, h7;
  float l0, l1, l2, l3, l4, l5, l6, l7;
  bf_split(va.x, h0, l0); bf_split(va.y, h1, l1);
  bf_split(va.z, h2, l2); bf_split(va.w, h3, l3);
  bf_split(vb.x, h4, l4); bf_split(vb.y, h5, l5);
  bf_split(vb.z, h6, l6); bf_split(vb.w, h7, l7);
  uint32x4 hu = {(h0 >> 16) | h1, (h2 >> 16) | h3,
                 (h4 >> 16) | h5, (h6 >> 16) | h7};
  uint32x4 lu = {pack_rn(l0, l1), pack_rn(l2, l3),
                 pack_rn(l4, l5), pack_rn(l6, l7)};
  hi = __builtin_bit_cast(short8, hu);
  lo = __builtin_bit_cast(short8, lu);
}

#define MFMA_BF16 __builtin_amdgcn_mfma_f32_16x16x32_bf16

// One k-tile, no synchronization. CURR/NXTR: float4[4] raw-fp32 B buffers
// ([0..1]=cols col0+ln15, [2..3]=cols col0+16+ln15), compile-time indexed.
#define BODY9(KT, CURR, NXTR)                                                  \
  do {                                                                         \
    if ((KT) + 1 < NT) {                                                       \
      const float* kp0 = kb0 + ((KT) + 1) * BK;                                \
      const float* kp1 = kb1 + ((KT) + 1) * BK;                                \
      NXTR[0] = *(const float4*)(kp0);                                         \
      NXTR[1] = *(const float4*)(kp0 + 4);                                     \
      NXTR[2] = *(const float4*)(kp1);                                         \
      NXTR[3] = *(const float4*)(kp1 + 4);                                     \
    }                                                                          \
    const int ktL = (KT) & 15;                                                 \
    short8 ahi[4], alo[4];                                                     \
    _Pragma("unroll") for (int mt = 0; mt < 4; ++mt) {                         \
      int off = (mt * 16 + ln15) * ASTRIDE + ktL * 32 + quad * 8;              \
      ahi[mt] = *(const short8*)(&sAhi[off]);                                  \
      alo[mt] = *(const short8*)(&sAlo[off]);                                  \
    }                                                                          \
    short8 bhi0, blo0, bhi1, blo1;                                             \
    split8(CURR[0], CURR[1], bhi0, blo0);                                      \
    split8(CURR[2], CURR[3], bhi1, blo1);                                      \
    _Pragma("unroll") for (int mt = 0; mt < 4; ++mt) {                         \
      acc[mt][0] = MFMA_BF16(ahi[mt], bhi0, acc[mt][0], 0, 0, 0);              \
      acc[mt][0] = MFMA_BF16(ahi[mt], blo0, acc[mt][0], 0, 0, 0);              \
      acc[mt][0] = MFMA_BF16(alo[mt], bhi0, acc[mt][0], 0, 0, 0);              \
      acc[mt][1] = MFMA_BF16(ahi[mt], bhi1, acc[mt][1], 0, 0, 0);              \
      acc[mt][1] = MFMA_BF16(ahi[mt], blo1, acc[mt][1], 0, 0, 0);              \
      acc[mt][1] = MFMA_BF16(alo[mt], bhi1, acc[mt][1], 0, 0, 0);              \
    }                                                                          \
  } while (0)

// ---------------------------------------------------------------------------
// attn_fused_v9: 1024 threads, 16 waves x (64 rows x 32 cols), single kernel
// ---------------------------------------------------------------------------
__global__ __launch_bounds__(1024, 4)
void attn_fused_v9(const float* __restrict__ Qg, const float* __restrict__ Kg,
                   const float* __restrict__ Tp, const float* __restrict__ Bp,
                   float* __restrict__ attn, float* __restrict__ conf) {
  __shared__ __align__(16) unsigned short sAhi[BM9 * ASTRIDE];  // 65 KB
  __shared__ __align__(16) unsigned short sAlo[BM9 * ASTRIDE];  // 65 KB
  __shared__ __align__(16) float sRedA[BM9][16];                // 4 KB
  __shared__ __align__(16) float sRedB[BM9][16];                // 4 KB

  const int tid = threadIdx.x;
  const int g = blockIdx.x;                       // 0..255
  const int batch = g & 31;                       // all q-blocks of a batch co-XCD
  const int q0 = (g >> 5) * BM9;                  // 8 q-chunks of 64
  const int ln = tid & 63, w = tid >> 6;          // w: 0..15 (one col-group each)
  const int ln15 = ln & 15, quad = ln >> 4;
  const int col0 = w * 32;

  const float* Qp = Qg + ((size_t)batch * NQ + q0) * ND;
  const float* Kp = Kg + (size_t)batch * NK * ND;

  // Per-lane B base: key = col0+ln15 (and +16 for nt1), k-chunk = quad*8.
  const float* kb0 = Kp + (size_t)(col0 + ln15) * ND + quad * 8;
  const float* kb1 = kb0 + 16 * ND;

  f32x4 acc[4][2];
#pragma unroll
  for (int mt = 0; mt < 4; ++mt)
#pragma unroll
    for (int nt = 0; nt < 2; ++nt) acc[mt][nt] = (f32x4){0.f, 0.f, 0.f, 0.f};

  // Stage one 512-k half of A (hi/lo bf16) with b128 LDS writes.
  auto stage_half = [&](int h) {
#pragma unroll
    for (int i = 0; i < 4; ++i) {
      int idx = tid + 1024 * i;
      int row = idx >> 6, kc8 = idx & 63;
      const float* p = Qp + (size_t)row * ND + h * 512 + kc8 * 8;
      float4 va = *(const float4*)(p);
      float4 vb = *(const float4*)(p + 4);
      unsigned h0, h1, h2, h3, h4, h5, h6, h7;
      float l0, l1, l2, l3, l4, l5, l6, l7;
      bf_split(va.x, h0, l0); bf_split(va.y, h1, l1);
      bf_split(va.z, h2, l2); bf_split(va.w, h3, l3);
      bf_split(vb.x, h4, l4); bf_split(vb.y, h5, l5);
      bf_split(vb.z, h6, l6); bf_split(vb.w, h7, l7);
      int off = row * ASTRIDE + kc8 * 8;
      *(uint4*)(&sAhi[off]) = make_uint4((h0 >> 16) | h1, (h2 >> 16) | h3,
                                         (h4 >> 16) | h5, (h6 >> 16) | h7);
      *(uint4*)(&sAlo[off]) = make_uint4(pack_rn(l0, l1), pack_rn(l2, l3),
                                         pack_rn(l4, l5), pack_rn(l6, l7));
    }
  };

  // ---- prologue: stage A half 0, load raw B(0) into registers ----
  stage_half(0);
  float4 pbA[4], pbB[4];
  pbA[0] = *(const float4*)(kb0);
  pbA[1] = *(const float4*)(kb0 + 4);
  pbA[2] = *(const float4*)(kb1);
  pbA[3] = *(const float4*)(kb1 + 4);
  __syncthreads();

  // ---- half 0: tiles 0..15, no barriers ----
#pragma unroll 1
  for (int kt = 0; kt < 16; kt += 2) {
    BODY9(kt, pbA, pbB);
    BODY9(kt + 1, pbB, pbA);
  }

  // ---- swap A image ----
  __syncthreads();          // all waves done reading half-0 image
  stage_half(1);
  __syncthreads();          // image ready

  // ---- half 1: tiles 16..31, no barriers ----
#pragma unroll 1
  for (int kt = 16; kt < 32; kt += 2) {
    BODY9(kt, pbA, pbB);
    BODY9(kt + 1, pbB, pbA);
  }

  // ============== epilogue: mask + softmax + confidence ==============
  const float NEGINF = -__builtin_inff();
  float rm[4][4];
#pragma unroll
  for (int mt = 0; mt < 4; ++mt)
#pragma unroll
    for (int rg = 0; rg < 4; ++rg) rm[mt][rg] = NEGINF;

#pragma unroll
  for (int nt = 0; nt < 2; ++nt) {
    int col = col0 + nt * 16 + ln15;
    bool msk = (Kp[(size_t)col * ND] == 0.0f);   // key feature 0 == 0 -> mask
#pragma unroll
    for (int mt = 0; mt < 4; ++mt)
#pragma unroll
      for (int rg = 0; rg < 4; ++rg) {
        float v = msk ? NEGINF : acc[mt][nt][rg];
        acc[mt][nt][rg] = v;
        rm[mt][rg] = fmaxf(rm[mt][rg], v);
      }
  }
#pragma unroll
  for (int mt = 0; mt < 4; ++mt)
#pragma unroll
    for (int rg = 0; rg < 4; ++rg) {
      float v = rm[mt][rg];
#pragma unroll
      for (int d = 1; d < 16; d <<= 1) v = fmaxf(v, __shfl_xor(v, d, 64));
      rm[mt][rg] = v;
    }
  if (ln15 == 0) {
#pragma unroll
    for (int mt = 0; mt < 4; ++mt)
#pragma unroll
      for (int rg = 0; rg < 4; ++rg)
        sRedA[mt * 16 + quad * 4 + rg][w] = rm[mt][rg];
  }
  __syncthreads();

  float gmax[4][4], gsum[4][4];
#pragma unroll
  for (int mt = 0; mt < 4; ++mt)
#pragma unroll
    for (int rg = 0; rg < 4; ++rg) {
      int row = mt * 16 + quad * 4 + rg;
      f32x4 p0 = *(const f32x4*)(&sRedA[row][0]);
      f32x4 p1 = *(const f32x4*)(&sRedA[row][4]);
      f32x4 p2 = *(const f32x4*)(&sRedA[row][8]);
      f32x4 p3 = *(const f32x4*)(&sRedA[row][12]);
      float m01 = fmaxf(fmaxf(fmaxf(p0[0], p0[1]), fmaxf(p0[2], p0[3])),
                        fmaxf(fmaxf(p1[0], p1[1]), fmaxf(p1[2], p1[3])));
      float m23 = fmaxf(fmaxf(fmaxf(p2[0], p2[1]), fmaxf(p2[2], p2[3])),
                        fmaxf(fmaxf(p3[0], p3[1]), fmaxf(p3[2], p3[3])));
      gmax[mt][rg] = fmaxf(m01, m23);
      gsum[mt][rg] = 0.f;
    }

#pragma unroll
  for (int nt = 0; nt < 2; ++nt)
#pragma unroll
    for (int mt = 0; mt < 4; ++mt)
#pragma unroll
      for (int rg = 0; rg < 4; ++rg) {
        float e = __expf(acc[mt][nt][rg] - gmax[mt][rg]);
        acc[mt][nt][rg] = e;
        gsum[mt][rg] += e;
      }
#pragma unroll
  for (int mt = 0; mt < 4; ++mt)
#pragma unroll
    for (int rg = 0; rg < 4; ++rg) {
      float v = gsum[mt][rg];
#pragma unroll
      for (int d = 1; d < 16; d <<= 1) v += __shfl_xor(v, d, 64);
      gsum[mt][rg] = v;
    }
  if (ln15 == 0) {
#pragma unroll
    for (int mt = 0; mt < 4; ++mt)
#pragma unroll
      for (int rg = 0; rg < 4; ++rg)
        sRedB[mt * 16 + quad * 4 + rg][w] = gsum[mt][rg];
  }
  __syncthreads();
#pragma unroll
  for (int mt = 0; mt < 4; ++mt)
#pragma unroll
    for (int rg = 0; rg < 4; ++rg) {
      int row = mt * 16 + quad * 4 + rg;
      f32x4 p0 = *(const f32x4*)(&sRedB[row][0]);
      f32x4 p1 = *(const f32x4*)(&sRedB[row][4]);
      f32x4 p2 = *(const f32x4*)(&sRedB[row][8]);
      f32x4 p3 = *(const f32x4*)(&sRedB[row][12]);
      gsum[mt][rg] = ((p0[0] + p0[1]) + (p0[2] + p0[3])) +
                     ((p1[0] + p1[1]) + (p1[2] + p1[3])) +
                     ((p2[0] + p2[1]) + (p2[2] + p2[3])) +
                     ((p3[0] + p3[1]) + (p3[2] + p3[3]));
    }

  float* outBase = attn + ((size_t)batch * NQ + q0) * NK;
#pragma unroll
  for (int mt = 0; mt < 4; ++mt)
#pragma unroll
    for (int rg = 0; rg < 4; ++rg) {
      int row = mt * 16 + quad * 4 + rg;
      float inv = 1.0f / gsum[mt][rg];
#pragma unroll
      for (int nt = 0; nt < 2; ++nt)
        outBase[(size_t)row * NK + col0 + nt * 16 + ln15] = acc[mt][nt][rg] * inv;
    }

  if (w == 0 && ln15 == 0) {   // lanes 0/16/32/48 x mt x rg cover rows 0..63
    float tv = Tp[0], bv = Bp[0];
#pragma unroll
    for (int mt = 0; mt < 4; ++mt)
#pragma unroll
      for (int rg = 0; rg < 4; ++rg) {
        int row = mt * 16 + quad * 4 + rg;
        float lse = gmax[mt][rg] + __logf(gsum[mt][rg]);
        float t = (lse + bv) * tv;
        conf[(size_t)batch * NQ + q0 + row] = 1.0f / (1.0f + __expf(-t));
      }
  }
}

extern "C" void kernel_launch(void* const* d_in, const int* in_sizes, int n_in,
                              void* d_out, int out_size, void* d_ws, size_t ws_size,
                              hipStream_t stream) {
  const float* q = (const float*)d_in[0];
  const float* k = (const float*)d_in[1];
  const float* temp = (const float*)d_in[2];
  const float* bias = (const float*)d_in[3];
  float* attn = (float*)d_out;
  float* conf = attn + (size_t)NB * NQ * NK;

  (void)d_ws; (void)ws_size;   // no workspace needed — single fused kernel
  hipLaunchKernelGGL(attn_fused_v9, dim3(NB * (NQ / BM9)), dim3(1024), 0, stream,
                     q, k, temp, bias, attn, conf);
}